// Round 1
// baseline (333.801 us; speedup 1.0000x reference)
//
#include <hip/hip_runtime.h>
#include <math.h>

#define NBOX   4096
#define MAXDET 300
#define CAP    3968          // boxes kept in LDS; overflow (V>CAP) spills to ws (never hit at V~2870)
#define NWORDS (NBOX / 32)

__device__ __forceinline__ float clipf(float v, float hi) {
  return fminf(fmaxf(v, 0.0f), hi);
}

struct SM {
  union {
    unsigned long long skey[NBOX];   // 32 KiB (sort phase)
    float4             obox[CAP];    // 62 KiB (NMS phase) — aliased, reg-staged handoff
  } u;
  unsigned int keepw[NWORDS];        // 512 B keep bitmap
  int kept_pos[MAXDET];              // 1.2 KiB
  int scal[8];                       // [0]=V, [1]=kept_total, [3]=K
};

__global__ __launch_bounds__(1024)
void nms_kernel(const float* __restrict__ boxes,
                const float* __restrict__ scores,
                const int*   __restrict__ labels,
                const float* __restrict__ nms_th,
                const float* __restrict__ cls_w,
                const int*   __restrict__ img_i,
                float* __restrict__ out,
                int B, int N,
                int* __restrict__ ws_sorted,
                float4* __restrict__ ws_ovf)
{
  __shared__ SM sm;
  const int b    = blockIdx.x;
  const int tid  = threadIdx.x;
  const int nthr = blockDim.x;

  const float* bx = boxes  + (size_t)b * N * 4;
  const float* sc = scores + (size_t)b * N;
  const int*   lb = labels + (size_t)b * N;

  // img_size: robust to int32 or float32 storage of the python scalar
  int   iv   = *img_i;
  float fimg = (iv > 0 && iv < (1 << 24)) ? (float)iv : __int_as_float(iv);
  float off_scale = fimg + 1.0f;

  // iou threshold = sigmoid(nms_thresh), computed in double then rounded to f32
  double xt = (double)(*nms_th);
  float  th = (float)(1.0 / (1.0 + exp(-xt)));

  if (tid < 8) sm.scal[tid] = 0;

  // ---- build 64-bit sort keys: (ordered-float(weighted) << 32) | (~idx) ----
  for (int i = tid; i < N; i += nthr) {
    float s = sc[i];
    unsigned long long key = (unsigned long long)(0xFFFFFFFFu - (unsigned)i);
    if (s > 0.3f) {                       // SCORE_THRESHOLD, strict >
      float w = s * cls_w[lb[i]];
      unsigned ubits = __float_as_uint(w);
      ubits = (ubits & 0x80000000u) ? ~ubits : (ubits | 0x80000000u);
      key |= ((unsigned long long)ubits << 32);
    }
    sm.u.skey[i] = key;
  }
  __syncthreads();

  // ---- bitonic sort, descending (stable via index in low bits) ----
  for (int k = 2; k <= N; k <<= 1) {
    for (int j = k >> 1; j > 0; j >>= 1) {
      for (int i = tid; i < N; i += nthr) {
        int l = i ^ j;
        if (l > i) {
          unsigned long long a = sm.u.skey[i];
          unsigned long long c = sm.u.skey[l];
          bool up = ((i & k) == 0);
          if (up ? (a < c) : (a > c)) { sm.u.skey[i] = c; sm.u.skey[l] = a; }
        }
      }
      __syncthreads();
    }
  }

  // ---- stage own keys to registers (frees skey LDS for obox alias), count valid ----
  unsigned long long kr[8];
  const int nper = N / nthr;               // 4
  int vc = 0;
  for (int m = 0; m < nper; ++m) {
    kr[m] = sm.u.skey[tid + m * nthr];
    vc += (int)((kr[m] >> 32) != 0ull);
  }
  atomicAdd(&sm.scal[0], vc);
  __syncthreads();
  const int V = sm.scal[0];                // valid boxes form a sorted prefix

  // ---- gather sorted boxes: clip + class offset; init keep bitmap ----
  for (int m = 0; m < nper; ++m) {
    int i = tid + m * nthr;
    unsigned orig = 0xFFFFFFFFu - (unsigned)(kr[m] & 0xFFFFFFFFull);
    ws_sorted[(size_t)b * N + i] = (int)orig;
    float4 bb = ((const float4*)bx)[orig];
    float off = (float)lb[orig] * off_scale;
    bb.x = clipf(bb.x, fimg) + off;
    bb.y = clipf(bb.y, fimg) + off;
    bb.z = clipf(bb.z, fimg) + off;
    bb.w = clipf(bb.w, fimg) + off;
    if (i < CAP) sm.u.obox[i] = bb;
    else         ws_ovf[(size_t)b * (NBOX - CAP) + (i - CAP)] = bb;
  }
  for (int w = tid; w < NWORDS; w += nthr) {
    int lo = w * 32;
    unsigned val;
    if      (V >= lo + 32) val = 0xFFFFFFFFu;
    else if (V <= lo)      val = 0u;
    else                   val = (1u << (V - lo)) - 1u;
    sm.keepw[w] = val;
  }
  __syncthreads();

  // ---- greedy NMS, tiles of 64, early-stop at 300 kept ----
  const int nt = (V + 63) >> 6;
  int TR = 0;
  for (int t = 0; t < nt; ++t) {
    // wave 0: resolve tile t exactly in greedy order
    if (tid < 64) {
      int i = t * 64 + tid;
      float4 bb = (i < CAP) ? sm.u.obox[i]
                            : ws_ovf[(size_t)b * (NBOX - CAP) + (i - CAP)];
      float ar = fmaxf(bb.z - bb.x, 0.0f) * fmaxf(bb.w - bb.y, 0.0f);
      unsigned long long alive =
          ((unsigned long long)sm.keepw[2 * t + 1] << 32) | sm.keepw[2 * t];
      unsigned long long rem = alive;
      while (rem) {
        int l = __builtin_ctzll(rem);
        rem &= rem - 1;
        float lx1 = __shfl(bb.x, l);
        float ly1 = __shfl(bb.y, l);
        float lx2 = __shfl(bb.z, l);
        float ly2 = __shfl(bb.w, l);
        float la  = __shfl(ar,   l);
        float xx1 = fmaxf(lx1, bb.x);
        float yy1 = fmaxf(ly1, bb.y);
        float xx2 = fminf(lx2, bb.z);
        float yy2 = fminf(ly2, bb.w);
        float inter = fmaxf(xx2 - xx1, 0.0f) * fmaxf(yy2 - yy1, 0.0f);
        float denom = la + ar;      // exact commutative add, matches ref order
        denom = denom - inter;
        denom = denom + 1e-9f;
        float iou = inter / denom;
        unsigned long long sup = __ballot(iou > th);
        sup &= ((~1ull) << l);      // only lanes > l
        sup &= alive;
        alive &= ~sup;
        rem   &= ~sup;
      }
      if (tid == 0) {
        sm.keepw[2 * t]     = (unsigned)alive;
        sm.keepw[2 * t + 1] = (unsigned)(alive >> 32);
        atomicAdd(&sm.scal[1], __builtin_popcountll(alive));
      }
    }
    __syncthreads();
    TR = t + 1;
    if (sm.scal[1] >= MAXDET) break;   // first 300 kept fixed -> nothing later matters

    // all threads: suppress later boxes with tile t's kept set
    int jstart = (t + 1) * 64;
    if (jstart < V) {
      unsigned long long alive =
          ((unsigned long long)sm.keepw[2 * t + 1] << 32) | sm.keepw[2 * t];
      if (alive) {
        for (int j = jstart + tid; j < V; j += nthr) {
          unsigned wj = sm.keepw[j >> 5];
          if (!((wj >> (j & 31)) & 1u)) continue;
          float4 bj = (j < CAP) ? sm.u.obox[j]
                                : ws_ovf[(size_t)b * (NBOX - CAP) + (j - CAP)];
          float aj = fmaxf(bj.z - bj.x, 0.0f) * fmaxf(bj.w - bj.y, 0.0f);
          unsigned long long rem = alive;
          bool suppressed = false;
          while (rem) {
            int l = __builtin_ctzll(rem);
            rem &= rem - 1;
            int i = t * 64 + l;
            float4 bi = (i < CAP) ? sm.u.obox[i]
                                  : ws_ovf[(size_t)b * (NBOX - CAP) + (i - CAP)];
            float ai = fmaxf(bi.z - bi.x, 0.0f) * fmaxf(bi.w - bi.y, 0.0f);
            float xx1 = fmaxf(bi.x, bj.x);
            float yy1 = fmaxf(bi.y, bj.y);
            float xx2 = fminf(bi.z, bj.z);
            float yy2 = fminf(bi.w, bj.w);
            float inter = fmaxf(xx2 - xx1, 0.0f) * fmaxf(yy2 - yy1, 0.0f);
            float denom = ai + aj;
            denom = denom - inter;
            denom = denom + 1e-9f;
            float iou = inter / denom;
            if (iou > th) { suppressed = true; break; }
          }
          if (suppressed) atomicAnd(&sm.keepw[j >> 5], ~(1u << (j & 31)));
        }
      }
    }
    __syncthreads();
  }

  // ---- compact: enumerate kept bits of resolved tiles, first 300 ----
  if (tid < NWORDS && tid >= TR * 2) sm.keepw[tid] = 0;  // unresolved region invalid
  __syncthreads();
  if (tid == 0) {
    int r = 0;
    for (int w = 0; w < NWORDS && r < MAXDET; ++w) {
      unsigned bits = sm.keepw[w];
      while (bits && r < MAXDET) {
        int l = __builtin_ctz(bits);
        bits &= bits - 1;
        sm.kept_pos[r++] = w * 32 + l;
      }
    }
    sm.scal[3] = r;
  }
  __syncthreads();
  const int K = sm.scal[3];

  // ---- write outputs (all 4 tensors fully, zeros elsewhere) ----
  float4* obx = (float4*)out;                        // B*300 float4
  float*  osc = out + (size_t)B * MAXDET * 4;
  float*  olb = osc + (size_t)B * MAXDET;
  float*  ovl = olb + (size_t)B * MAXDET;
  for (int r = tid; r < MAXDET; r += nthr) {
    size_t slot = (size_t)b * MAXDET + r;
    if (r < K) {
      int i    = sm.kept_pos[r];
      int orig = ws_sorted[(size_t)b * N + i];
      float4 bb = ((const float4*)bx)[orig];
      bb.x = clipf(bb.x, fimg);
      bb.y = clipf(bb.y, fimg);
      bb.z = clipf(bb.z, fimg);
      bb.w = clipf(bb.w, fimg);
      obx[slot] = bb;
      osc[slot] = sc[orig];
      olb[slot] = (float)lb[orig];
      ovl[slot] = 1.0f;
    } else {
      obx[slot] = make_float4(0.f, 0.f, 0.f, 0.f);
      osc[slot] = 0.0f;
      olb[slot] = 0.0f;
      ovl[slot] = 0.0f;
    }
  }
}

extern "C" void kernel_launch(void* const* d_in, const int* in_sizes, int n_in,
                              void* d_out, int out_size, void* d_ws, size_t ws_size,
                              hipStream_t stream) {
  const float* boxes      = (const float*)d_in[0];
  const float* scores     = (const float*)d_in[1];
  const int*   labels     = (const int*)d_in[2];
  const float* nms_thresh = (const float*)d_in[3];
  const float* cls_w      = (const float*)d_in[4];
  const int*   img_sz     = (const int*)d_in[5];

  int B = out_size / (MAXDET * 7);       // 4 box + score + label + valid per det
  int N = in_sizes[1] / B;               // scores is (B,N)

  int*    ws_sorted = (int*)d_ws;                                   // B*N ints
  float4* ws_ovf    = (float4*)((char*)d_ws + (size_t)B * N * 4);   // overflow boxes

  nms_kernel<<<dim3(B), dim3(1024), 0, stream>>>(
      boxes, scores, labels, nms_thresh, cls_w, img_sz,
      (float*)d_out, B, N, ws_sorted, ws_ovf);
}

// Round 2
// 307.326 us; speedup vs baseline: 1.0861x; 1.0861x over previous
//
#include <hip/hip_runtime.h>
#include <math.h>

#define NBOX   4096
#define NTHR   1024
#define MAXDET 300
#define CAP    3968          // boxes kept in LDS; overflow spills to ws (V~2870 never hits it)
#define NWORDS (NBOX / 32)

typedef unsigned long long ull;

__device__ __forceinline__ float clipf(float v, float hi) {
  return fminf(fmaxf(v, 0.0f), hi);
}

// =================== kernel A: build keys + hybrid bitonic sort ===================
// key = (ordered_float_bits(weighted_score) << 32) | (0xFFFFFFFF - idx); descending
// sort == argsort(-weighted, stable). Invalid (score<=0.3) have high32=0 -> tail.
struct SMA { ull skey[NBOX]; int vcount; };

__global__ __launch_bounds__(NTHR)
void sort_kernel(const float* __restrict__ scores,
                 const int*   __restrict__ labels,
                 const float* __restrict__ cls_w,
                 int* __restrict__ ws_sorted,
                 int* __restrict__ ws_V,
                 int N)
{
  __shared__ SMA sm;
  const int b   = blockIdx.x;
  const int tid = threadIdx.x;
  const float* sc = scores + (size_t)b * N;
  const int*   lb = labels + (size_t)b * N;

  if (tid == 0) sm.vcount = 0;
  for (int i = tid; i < NBOX; i += NTHR) {
    float s = sc[i];
    ull key = (ull)(0xFFFFFFFFu - (unsigned)i);
    if (s > 0.3f) {                       // SCORE_THRESHOLD, strict >
      float w = s * cls_w[lb[i]];
      unsigned ub = __float_as_uint(w);
      ub = (ub & 0x80000000u) ? ~ub : (ub | 0x80000000u);
      key |= ((ull)ub << 32);
    }
    sm.skey[i] = key;
  }
  __syncthreads();

  // wave w owns region [w*256, w*256+256); lane holds elements wbase + r*64 + lane
  const int lane  = tid & 63;
  const int wbase = (tid >> 6) << 8;
  ull v0, v1, v2, v3;

  #define LOADV  { v0 = sm.skey[wbase      + lane]; v1 = sm.skey[wbase + 64 + lane]; \
                   v2 = sm.skey[wbase +128 + lane]; v3 = sm.skey[wbase +192 + lane]; }
  #define STOREV { sm.skey[wbase      + lane] = v0; sm.skey[wbase + 64 + lane] = v1; \
                   sm.skey[wbase +128 + lane] = v2; sm.skey[wbase +192 + lane] = v3; }
  // register-pair compare-swap: va is lower element (offset eo), vb = va-partner at +j
  #define CSWAP_REG(va, vb, eo) { int e_ = wbase + (eo) + lane;                      \
      if ((((e_) & k) == 0) ? ((va) < (vb)) : ((va) > (vb))) { ull t_ = (va); (va) = (vb); (vb) = t_; } }
  // shfl compare-swap across lanes (j <= 32)
  #define CSWAP_SHFL(vr, eo) { int e_ = wbase + (eo) + lane;                         \
      ull c_ = __shfl_xor((vr), j);                                                  \
      bool km_ = ((((e_) & k) == 0) == ((lane & j) == 0));                           \
      (vr) = km_ ? ((vr) > c_ ? (vr) : c_) : ((vr) < c_ ? (vr) : c_); }
  #define LOCALPHASES(jmax) {                                                        \
      for (int j = (jmax); j >= 1; j >>= 1) {                                        \
        if (j == 128)     { CSWAP_REG(v0, v2, 0);  CSWAP_REG(v1, v3, 64);  }         \
        else if (j == 64) { CSWAP_REG(v0, v1, 0);  CSWAP_REG(v2, v3, 128); }         \
        else { CSWAP_SHFL(v0, 0); CSWAP_SHFL(v1, 64); CSWAP_SHFL(v2, 128); CSWAP_SHFL(v3, 192); } } }

  // stages k=2..256: fully wave-local, zero barriers
  LOADV;
  for (int k = 2; k <= 256; k <<= 1) { LOCALPHASES(k >> 1); }
  STOREV;
  __syncthreads();

  // stages k=512..4096: cross phases (j>=256) in LDS, rest wave-local
  for (int k = 512; k <= NBOX; k <<= 1) {
    for (int j = k >> 1; j >= 256; j >>= 1) {
      for (int i = tid; i < NBOX; i += NTHR) {
        int l = i ^ j;
        if (l > i) {
          ull a = sm.skey[i], c = sm.skey[l];
          if (((i & k) == 0) ? (a < c) : (a > c)) { sm.skey[i] = c; sm.skey[l] = a; }
        }
      }
      __syncthreads();
    }
    LOADV;
    LOCALPHASES(128);
    STOREV;           // keep LDS canonical for next stage's cross phases
    __syncthreads();
  }

  // emit sorted original indices (from registers) + valid count
  int* wsb = ws_sorted + (size_t)b * N;
  wsb[wbase       + lane] = (int)(0xFFFFFFFFu - (unsigned)v0);
  wsb[wbase +  64 + lane] = (int)(0xFFFFFFFFu - (unsigned)v1);
  wsb[wbase + 128 + lane] = (int)(0xFFFFFFFFu - (unsigned)v2);
  wsb[wbase + 192 + lane] = (int)(0xFFFFFFFFu - (unsigned)v3);
  int vc = (int)((v0 >> 32) != 0) + (int)((v1 >> 32) != 0)
         + (int)((v2 >> 32) != 0) + (int)((v3 >> 32) != 0);
  atomicAdd(&sm.vcount, vc);
  __syncthreads();
  if (tid == 0) ws_V[b] = sm.vcount;
}

// =================== kernel B: greedy NMS + compaction ===================
struct SMB {
  float4       obox[CAP];            // clipped + class-offset boxes, sorted order
  unsigned int keepw[NWORDS];
  int          kept_pos[MAXDET];
  int          scal[4];              // [1]=kept_total, [3]=K
};

__global__ __launch_bounds__(NTHR)
void nms_kernel(const float* __restrict__ boxes,
                const float* __restrict__ scores,
                const int*   __restrict__ labels,
                const float* __restrict__ nms_th,
                const float* __restrict__ cls_w,
                const int*   __restrict__ img_i,
                float* __restrict__ out,
                int B, int N,
                const int* __restrict__ ws_sorted,
                const int* __restrict__ ws_V,
                float4* __restrict__ ws_ovf)
{
  __shared__ SMB sm;
  const int b    = blockIdx.x;
  const int tid  = threadIdx.x;

  const float* bx = boxes  + (size_t)b * N * 4;
  const float* sc = scores + (size_t)b * N;
  const int*   lb = labels + (size_t)b * N;
  const int*   so = ws_sorted + (size_t)b * N;

  int   iv   = *img_i;
  float fimg = (iv > 0 && iv < (1 << 24)) ? (float)iv : __int_as_float(iv);
  float off_scale = fimg + 1.0f;
  double xt = (double)(*nms_th);
  float  th = (float)(1.0 / (1.0 + exp(-xt)));

  const int V = ws_V[b];
  if (tid < 4) sm.scal[tid] = 0;

  // gather sorted boxes: clip + class offset
  for (int m = 0; m < 4; ++m) {
    int i = tid + m * NTHR;
    int orig = so[i];
    float4 bb = ((const float4*)bx)[orig];
    float off = (float)lb[orig] * off_scale;
    bb.x = clipf(bb.x, fimg) + off;
    bb.y = clipf(bb.y, fimg) + off;
    bb.z = clipf(bb.z, fimg) + off;
    bb.w = clipf(bb.w, fimg) + off;
    if (i < CAP) sm.obox[i] = bb;
    else         ws_ovf[(size_t)b * (NBOX - CAP) + (i - CAP)] = bb;
  }
  for (int w = tid; w < NWORDS; w += NTHR) {
    int lo = w * 32;
    unsigned val;
    if      (V >= lo + 32) val = 0xFFFFFFFFu;
    else if (V <= lo)      val = 0u;
    else                   val = (1u << (V - lo)) - 1u;
    sm.keepw[w] = val;
  }
  __syncthreads();

  // greedy NMS, tiles of 64, early-stop once 300 kept
  const int nt = (V + 63) >> 6;
  int TR = 0;
  for (int t = 0; t < nt; ++t) {
    if (tid < 64) {
      // lane j: precompute 64-bit "suppressed-by-i" mask vs all tile boxes (broadcast LDS reads)
      int i0 = t * 64;
      int me = i0 + tid;
      float4 bb = (me < CAP) ? sm.obox[me]
                             : ws_ovf[(size_t)b * (NBOX - CAP) + (me - CAP)];
      float ar = fmaxf(bb.z - bb.x, 0.0f) * fmaxf(bb.w - bb.y, 0.0f);
      ull supby = 0;
      for (int l = 0; l < 64; ++l) {
        int i = i0 + l;
        float4 bi = (i < CAP) ? sm.obox[i]
                              : ws_ovf[(size_t)b * (NBOX - CAP) + (i - CAP)];
        float ai = fmaxf(bi.z - bi.x, 0.0f) * fmaxf(bi.w - bi.y, 0.0f);
        float xx1 = fmaxf(bi.x, bb.x);
        float yy1 = fmaxf(bi.y, bb.y);
        float xx2 = fminf(bi.z, bb.z);
        float yy2 = fminf(bi.w, bb.w);
        float inter = fmaxf(xx2 - xx1, 0.0f) * fmaxf(yy2 - yy1, 0.0f);
        float denom = ai + ar;      // (areas[i] + areas[j]) - inter + 1e-9, ref order
        denom = denom - inter;
        denom = denom + 1e-9f;
        float iou = inter / denom;
        if (iou > th) supby |= (1ull << l);
      }
      // serial greedy resolve: pure bit ops now
      ull alive = ((ull)sm.keepw[2 * t + 1] << 32) | sm.keepw[2 * t];
      ull rem = alive;
      while (rem) {
        int l = __builtin_ctzll(rem);
        rem &= rem - 1;
        ull sup = __ballot((supby >> l) & 1ull);
        sup &= ((~1ull) << l);
        sup &= alive;
        alive &= ~sup;
        rem   &= ~sup;
      }
      if (tid == 0) {
        sm.keepw[2 * t]     = (unsigned)alive;
        sm.keepw[2 * t + 1] = (unsigned)(alive >> 32);
        atomicAdd(&sm.scal[1], __builtin_popcountll(alive));
      }
    }
    __syncthreads();
    TR = t + 1;
    if (sm.scal[1] >= MAXDET) break;   // first 300 kept are fixed

    // all threads: suppress later boxes with tile t's kept set
    int jstart = (t + 1) * 64;
    if (jstart < V) {
      ull alive = ((ull)sm.keepw[2 * t + 1] << 32) | sm.keepw[2 * t];
      if (alive) {
        for (int j = jstart + tid; j < V; j += NTHR) {
          unsigned wj = sm.keepw[j >> 5];
          if (!((wj >> (j & 31)) & 1u)) continue;
          float4 bj = (j < CAP) ? sm.obox[j]
                                : ws_ovf[(size_t)b * (NBOX - CAP) + (j - CAP)];
          float aj = fmaxf(bj.z - bj.x, 0.0f) * fmaxf(bj.w - bj.y, 0.0f);
          ull rem = alive;
          bool suppressed = false;
          while (rem) {
            int l = __builtin_ctzll(rem);
            rem &= rem - 1;
            int i = t * 64 + l;
            float4 bi = (i < CAP) ? sm.obox[i]
                                  : ws_ovf[(size_t)b * (NBOX - CAP) + (i - CAP)];
            float ai = fmaxf(bi.z - bi.x, 0.0f) * fmaxf(bi.w - bi.y, 0.0f);
            float xx1 = fmaxf(bi.x, bj.x);
            float yy1 = fmaxf(bi.y, bj.y);
            float xx2 = fminf(bi.z, bj.z);
            float yy2 = fminf(bi.w, bj.w);
            float inter = fmaxf(xx2 - xx1, 0.0f) * fmaxf(yy2 - yy1, 0.0f);
            float denom = ai + aj;
            denom = denom - inter;
            denom = denom + 1e-9f;
            float iou = inter / denom;
            if (iou > th) { suppressed = true; break; }
          }
          if (suppressed) atomicAnd(&sm.keepw[j >> 5], ~(1u << (j & 31)));
        }
      }
    }
    __syncthreads();
  }

  // compact kept bits of resolved tiles
  if (tid < NWORDS && tid >= TR * 2) sm.keepw[tid] = 0;
  __syncthreads();
  if (tid == 0) {
    int r = 0;
    for (int w = 0; w < NWORDS && r < MAXDET; ++w) {
      unsigned bits = sm.keepw[w];
      while (bits && r < MAXDET) {
        int l = __builtin_ctz(bits);
        bits &= bits - 1;
        sm.kept_pos[r++] = w * 32 + l;
      }
    }
    sm.scal[3] = r;
  }
  __syncthreads();
  const int K = sm.scal[3];

  // outputs
  float4* obx = (float4*)out;
  float*  osc = out + (size_t)B * MAXDET * 4;
  float*  olb = osc + (size_t)B * MAXDET;
  float*  ovl = olb + (size_t)B * MAXDET;
  for (int r = tid; r < MAXDET; r += NTHR) {
    size_t slot = (size_t)b * MAXDET + r;
    if (r < K) {
      int i    = sm.kept_pos[r];
      int orig = so[i];
      float4 bb = ((const float4*)bx)[orig];
      bb.x = clipf(bb.x, fimg);
      bb.y = clipf(bb.y, fimg);
      bb.z = clipf(bb.z, fimg);
      bb.w = clipf(bb.w, fimg);
      obx[slot] = bb;
      osc[slot] = sc[orig];
      olb[slot] = (float)lb[orig];
      ovl[slot] = 1.0f;
    } else {
      obx[slot] = make_float4(0.f, 0.f, 0.f, 0.f);
      osc[slot] = 0.0f;
      olb[slot] = 0.0f;
      ovl[slot] = 0.0f;
    }
  }
}

extern "C" void kernel_launch(void* const* d_in, const int* in_sizes, int n_in,
                              void* d_out, int out_size, void* d_ws, size_t ws_size,
                              hipStream_t stream) {
  const float* boxes      = (const float*)d_in[0];
  const float* scores     = (const float*)d_in[1];
  const int*   labels     = (const int*)d_in[2];
  const float* nms_thresh = (const float*)d_in[3];
  const float* cls_w      = (const float*)d_in[4];
  const int*   img_sz     = (const int*)d_in[5];

  int B = out_size / (MAXDET * 7);
  int N = in_sizes[1] / B;               // 4096

  int*    ws_sorted = (int*)d_ws;                                        // B*N ints
  int*    ws_V      = (int*)((char*)d_ws + (size_t)B * N * 4);           // B ints
  float4* ws_ovf    = (float4*)((char*)d_ws + (size_t)B * N * 4 + 1024); // overflow boxes

  sort_kernel<<<dim3(B), dim3(NTHR), 0, stream>>>(scores, labels, cls_w,
                                                  ws_sorted, ws_V, N);
  nms_kernel<<<dim3(B), dim3(NTHR), 0, stream>>>(boxes, scores, labels,
                                                 nms_thresh, cls_w, img_sz,
                                                 (float*)d_out, B, N,
                                                 ws_sorted, ws_V, ws_ovf);
}